// Round 3
// baseline (257.938 us; speedup 1.0000x reference)
//
#include <hip/hip_runtime.h>
#include <math.h>

#define N_NODES 200000
#define NF 128
#define NT 32
#define NS 32
#define NG 128
#define SPLITS 16
#define TILE 64
#define XPAD 132   // x row stride (floats): odd multiple of 16B -> b128 reads 2-way-free
#define NHPAD 36   // nh row stride: bank = (4j+t)%32 distinct across t -> conflict-free b32

__device__ __forceinline__ float rcp_fast(float x) { return __builtin_amdgcn_rcpf(x); }

__global__ __launch_bounds__(256, 3)
void ect_kernel(const float* __restrict__ x,
                const int* __restrict__ batch,   // int32 (JAX demotes int64)
                const float* __restrict__ v,
                float* __restrict__ out)
{
    __shared__ float x_lds[TILE * XPAD];    // 33792 B
    __shared__ float nh_lds[TILE * NHPAD];  //  9216 B  -> 43 KB total, 3 blocks/CU

    const int tid   = threadIdx.x;
    const int g     = blockIdx.x >> 4;
    const int split = blockIdx.x & (SPLITS - 1);

    // graph range via binary search on sorted batch (uniform -> scalar path)
    int lo = 0, hi = N_NODES;
    while (lo < hi) { int mid = (lo + hi) >> 1; if (batch[mid] < g) lo = mid + 1; else hi = mid; }
    const int g_start = lo;
    hi = N_NODES;
    while (lo < hi) { int mid = (lo + hi) >> 1; if (batch[mid] < g + 1) lo = mid + 1; else hi = mid; }
    const int g_end = lo;

    const int count = g_end - g_start;
    const int chunk = (count + SPLITS - 1) / SPLITS;
    int my_start = g_start + split * chunk;
    if (my_start > g_end) my_start = g_end;
    int my_end = my_start + chunk;
    if (my_end > g_end) my_end = g_end;
    const int my_count = my_end - my_start;

    const float L    = 144.26950408889634f;  // SCALE * log2(e)
    const float dlin = 2.2f / 31.0f;

    // sigmoid-phase ownership: thread -> (t, s = sb + 8k, k=0..3)
    const int t  = tid & 31;
    const int sb = tid >> 5;
    float acc0[4] = {0.f, 0.f, 0.f, 0.f};
    float acc1[4] = {0.f, 0.f, 0.f, 0.f};
    float negA[4];
    #pragma unroll
    for (int k = 0; k < 4; ++k) {
        float lin_s = -1.1f + (float)(sb + 8 * k) * dlin;
        negA[k] = -L * lin_s;
    }

    // matvec ownership: wave wu owns thetas [8wu, 8wu+8), lane = node
    const int node = tid & 63;
    // readfirstlane makes the wave id an SGPR -> v addresses are provably
    // wave-uniform -> compiler emits s_load; v feeds v_fma_f32 as the scalar operand
    const int wu = __builtin_amdgcn_readfirstlane(tid >> 6);
    const float* __restrict__ vbase = v + (size_t)wu * 8 * NF;

    for (int tile_start = my_start; tile_start < my_end; tile_start += TILE) {
        const int nvalid = min(TILE, my_end - tile_start);
        __syncthreads();   // protect LDS from previous iteration's readers

        // stage x tile (coalesced float4 global reads)
        #pragma unroll
        for (int j = 0; j < 8; ++j) {
            int idx4 = j * 256 + tid;      // 0..2047
            int nn   = idx4 >> 5;          // node 0..63
            int f4   = idx4 & 31;
            if (nn < nvalid) {
                float4 val = *(const float4*)&x[(size_t)(tile_start + nn) * NF + f4 * 4];
                *(float4*)&x_lds[nn * XPAD + f4 * 4] = val;
            }
        }
        __syncthreads();

        // nh = x . v^T : lane = node, 8 thetas from SGPR-held v
        if (node < nvalid) {
            float nh8[8] = {0.f,0.f,0.f,0.f,0.f,0.f,0.f,0.f};
            #pragma unroll 4
            for (int f4 = 0; f4 < 32; ++f4) {
                float4 xv = *(const float4*)&x_lds[node * XPAD + f4 * 4];
                #pragma unroll
                for (int tt = 0; tt < 8; ++tt) {
                    const float* vp = &vbase[tt * NF + f4 * 4];  // wave-uniform address
                    nh8[tt] = fmaf(xv.x, vp[0], nh8[tt]);
                    nh8[tt] = fmaf(xv.y, vp[1], nh8[tt]);
                    nh8[tt] = fmaf(xv.z, vp[2], nh8[tt]);
                    nh8[tt] = fmaf(xv.w, vp[3], nh8[tt]);
                }
            }
            *(float4*)&nh_lds[node * NHPAD + wu * 8]     = make_float4(nh8[0], nh8[1], nh8[2], nh8[3]);
            *(float4*)&nh_lds[node * NHPAD + wu * 8 + 4] = make_float4(nh8[4], nh8[5], nh8[6], nh8[7]);
        }
        __syncthreads();

        // sigmoid accumulate: acc += 1/(1 + exp2(L*h - L*lin_s)); 2 nodes/iter for ILP
        int j = 0;
        for (; j + 2 <= nvalid; j += 2) {
            float h0 = nh_lds[j * NHPAD + t];
            float h1 = nh_lds[(j + 1) * NHPAD + t];
            #pragma unroll
            for (int k = 0; k < 4; ++k) {
                float e0 = __builtin_amdgcn_exp2f(fmaf(L, h0, negA[k]));
                float e1 = __builtin_amdgcn_exp2f(fmaf(L, h1, negA[k]));
                acc0[k] += rcp_fast(1.0f + e0);
                acc1[k] += rcp_fast(1.0f + e1);
            }
        }
        if (j < nvalid) {
            float h0 = nh_lds[j * NHPAD + t];
            #pragma unroll
            for (int k = 0; k < 4; ++k) {
                float e0 = __builtin_amdgcn_exp2f(fmaf(L, h0, negA[k]));
                acc0[k] += rcp_fast(1.0f + e0);
            }
        }
    }

    // subtract the constant pad term exactly: my_count * sigmoid(SCALE*(lin_s - R))
    #pragma unroll
    for (int k = 0; k < 4; ++k) {
        int s = sb + 8 * k;
        float lin_s = -1.1f + (float)s * dlin;
        float cs = rcp_fast(1.0f + __builtin_amdgcn_exp2f(L * (1.1f - lin_s)));
        float val = (acc0[k] + acc1[k]) - (float)my_count * cs;
        atomicAdd(&out[(size_t)g * (NS * NT) + s * NT + t], val);
    }
}

extern "C" void kernel_launch(void* const* d_in, const int* in_sizes, int n_in,
                              void* d_out, int out_size, void* d_ws, size_t ws_size,
                              hipStream_t stream) {
    const float* x     = (const float*)d_in[0];
    const int*   batch = (const int*)d_in[1];
    const float* v     = (const float*)d_in[3];
    float*       out   = (float*)d_out;

    hipMemsetAsync(d_out, 0, (size_t)out_size * sizeof(float), stream);
    ect_kernel<<<dim3(NG * SPLITS), dim3(256), 0, stream>>>(x, batch, v, out);
}